// Round 2
// baseline (3203.245 us; speedup 1.0000x reference)
//
#include <hip/hip_runtime.h>
#include <math.h>

#define N_NODES 100000
#define N_EDGES 1600000
// IN=128, HD=128, H=4, D=32

// ---- ordered-uint encoding for float atomicMax ----
__device__ __forceinline__ unsigned f2o(float f) {
    unsigned b = __float_as_uint(f);
    return (b & 0x80000000u) ? ~b : (b | 0x80000000u);
}
__device__ __forceinline__ float o2f(unsigned u) {
    return (u & 0x80000000u) ? __uint_as_float(u ^ 0x80000000u) : __uint_as_float(~u);
}

// ============================================================
// Kernel 1: fused 4-way projection GEMM
//   C[M=100000, 128] = feat[M,128] @ W[128,128] + b, for W in {Wq,Wk,Wv,Wskip}
// ============================================================
__global__ __launch_bounds__(256) void gemm_proj(
    const float* __restrict__ feat,
    const float* __restrict__ Wq, const float* __restrict__ bq,
    const float* __restrict__ Wk, const float* __restrict__ bk,
    const float* __restrict__ Wv, const float* __restrict__ bv,
    const float* __restrict__ Ws, const float* __restrict__ bs,
    float* __restrict__ qo, float* __restrict__ ko,
    float* __restrict__ vo, float* __restrict__ so)
{
    __shared__ float As[16][128];   // [kk][row]
    __shared__ float Bs[16][128];   // [kk][col]

    const int m0 = blockIdx.x * 128;
    const int w  = blockIdx.y;
    const float* W    = (w == 0) ? Wq : (w == 1) ? Wk : (w == 2) ? Wv : Ws;
    const float* bias = (w == 0) ? bq : (w == 1) ? bk : (w == 2) ? bv : bs;
    float* out        = (w == 0) ? qo : (w == 1) ? ko : (w == 2) ? vo : so;

    const int t  = threadIdx.x;
    const int tx = t & 15;       // col group
    const int ty = t >> 4;       // row group

    float acc[8][8];
    #pragma unroll
    for (int i = 0; i < 8; i++)
        #pragma unroll
        for (int j = 0; j < 8; j++) acc[i][j] = 0.f;

    const int lm = t >> 1;            // 0..127
    const int lk = (t & 1) * 8;       // 0 or 8
    const int wk = t >> 4;            // 0..15 (kk)
    const int wn = (t & 15) * 8;      // 0..120

    for (int k0 = 0; k0 < 128; k0 += 16) {
        int row = m0 + lm;
        int rc  = row < N_NODES ? row : (N_NODES - 1);
        const float4* fr = (const float4*)(feat + (size_t)rc * 128 + k0 + lk);
        float4 f0 = fr[0];
        float4 f1 = fr[1];
        As[lk + 0][lm] = f0.x; As[lk + 1][lm] = f0.y;
        As[lk + 2][lm] = f0.z; As[lk + 3][lm] = f0.w;
        As[lk + 4][lm] = f1.x; As[lk + 5][lm] = f1.y;
        As[lk + 6][lm] = f1.z; As[lk + 7][lm] = f1.w;

        const float4* wr = (const float4*)(W + (size_t)(k0 + wk) * 128 + wn);
        *(float4*)&Bs[wk][wn]     = wr[0];
        *(float4*)&Bs[wk][wn + 4] = wr[1];

        __syncthreads();

        #pragma unroll
        for (int kk = 0; kk < 16; kk++) {
            float4 a0 = *(const float4*)&As[kk][ty * 8];
            float4 a1 = *(const float4*)&As[kk][ty * 8 + 4];
            float4 b0 = *(const float4*)&Bs[kk][tx * 8];
            float4 b1 = *(const float4*)&Bs[kk][tx * 8 + 4];
            float av[8] = {a0.x, a0.y, a0.z, a0.w, a1.x, a1.y, a1.z, a1.w};
            float bw[8] = {b0.x, b0.y, b0.z, b0.w, b1.x, b1.y, b1.z, b1.w};
            #pragma unroll
            for (int i = 0; i < 8; i++)
                #pragma unroll
                for (int j = 0; j < 8; j++)
                    acc[i][j] += av[i] * bw[j];
        }
        __syncthreads();
    }

    float bvv[8];
    #pragma unroll
    for (int j = 0; j < 8; j++) bvv[j] = bias[tx * 8 + j];

    #pragma unroll
    for (int i = 0; i < 8; i++) {
        int row = m0 + ty * 8 + i;
        if (row < N_NODES) {
            float4 r0, r1;
            r0.x = acc[i][0] + bvv[0]; r0.y = acc[i][1] + bvv[1];
            r0.z = acc[i][2] + bvv[2]; r0.w = acc[i][3] + bvv[3];
            r1.x = acc[i][4] + bvv[4]; r1.y = acc[i][5] + bvv[5];
            r1.z = acc[i][6] + bvv[6]; r1.w = acc[i][7] + bvv[7];
            float* op = out + (size_t)row * 128 + tx * 8;
            *(float4*)op       = r0;
            *(float4*)(op + 4) = r1;
        }
    }
}

// ============================================================
// Kernel 2: edge scores a[e,h] = dot(q[src],k[dst])/sqrt(D), atomicMax m[dst,h]
//   8 lanes per (edge,head) -> 32 lanes per edge -> E*32 threads total
// ============================================================
__global__ __launch_bounds__(256) void edge_scores(
    const float* __restrict__ q, const float* __restrict__ k,
    const int* __restrict__ src, const int* __restrict__ dst,
    float* __restrict__ a, unsigned* __restrict__ m)
{
    int t = blockIdx.x * 256 + threadIdx.x;
    int p = t >> 3;            // (edge, head) pair
    int e = p >> 2;
    int h = p & 3;
    int c = t & 7;
    if (e >= N_EDGES) return;
    int sN = src[e], dN = dst[e];
    float4 qv = *((const float4*)(q + (size_t)sN * 128 + h * 32) + c);
    float4 kv = *((const float4*)(k + (size_t)dN * 128 + h * 32) + c);
    float sdot = qv.x * kv.x + qv.y * kv.y + qv.z * kv.z + qv.w * kv.w;
    sdot += __shfl_xor(sdot, 1);
    sdot += __shfl_xor(sdot, 2);
    sdot += __shfl_xor(sdot, 4);
    if (c == 0) {
        float sc = sdot * 0.17677669529663687f;  // 1/sqrt(32)
        a[(size_t)e * 4 + h] = sc;
        atomicMax(m + (size_t)dN * 4 + h, f2o(sc));
    }
}

// ============================================================
// Kernel 3: exp + denominator + unnormalized weighted scatter-sum
//   32 lanes per edge (one float4 chunk of the 128-wide v row per lane)
// ============================================================
__global__ __launch_bounds__(256) void edge_accum(
    const float* __restrict__ a, const unsigned* __restrict__ m,
    const float* __restrict__ v,
    const int* __restrict__ src, const int* __restrict__ dst,
    float* __restrict__ den, float* __restrict__ aggu)
{
    int t = blockIdx.x * 256 + threadIdx.x;
    int e = t >> 5;
    int c = t & 31;            // float4 chunk index 0..31
    if (e >= N_EDGES) return;
    int h = c >> 3;
    int sN = src[e], dN = dst[e];
    float sc = a[(size_t)e * 4 + h];
    float mo = o2f(m[(size_t)dN * 4 + h]);
    float ex = __expf(sc - mo);
    if ((c & 7) == 0) atomicAdd(den + (size_t)dN * 4 + h, ex);
    float4 vv = *((const float4*)(v + (size_t)sN * 128) + c);
    float* ag = aggu + (size_t)dN * 128 + c * 4;
    atomicAdd(ag + 0, ex * vv.x);
    atomicAdd(ag + 1, ex * vv.y);
    atomicAdd(ag + 2, ex * vv.z);
    atomicAdd(ag + 3, ex * vv.w);
}

// ============================================================
// Kernel 4: per-node epilogue — normalize, gate, LayerNorm, PReLU
// ============================================================
__global__ __launch_bounds__(256) void finalize(
    const float* __restrict__ den, const float* __restrict__ skip,
    const float* __restrict__ wg, const float* __restrict__ bg,
    const float* __restrict__ gamma, const float* __restrict__ beta,
    const float* __restrict__ pa,
    float* __restrict__ out)
{
    int wid  = threadIdx.x >> 6;
    int lane = threadIdx.x & 63;
    int n = blockIdx.x * 4 + wid;
    if (n >= N_NODES) return;
    int j0 = lane, j1 = lane + 64;

    float ag0 = out[(size_t)n * 128 + j0];
    float ag1 = out[(size_t)n * 128 + j1];
    float d0 = den[(size_t)n * 4 + (j0 >> 5)];
    float d1 = den[(size_t)n * 4 + (j1 >> 5)];
    float r0 = ag0 / d0;
    float r1 = ag1 / d1;
    float s0 = skip[(size_t)n * 128 + j0];
    float s1 = skip[(size_t)n * 128 + j1];

    float gs = s0 * wg[j0] + r0 * wg[128 + j0] + (s0 - r0) * wg[256 + j0]
             + s1 * wg[j1] + r1 * wg[128 + j1] + (s1 - r1) * wg[256 + j1];
    #pragma unroll
    for (int o = 1; o < 64; o <<= 1) gs += __shfl_xor(gs, o);
    float g = 1.f / (1.f + __expf(-(gs + bg[0])));

    r0 = g * s0 + (1.f - g) * r0;
    r1 = g * s1 + (1.f - g) * r1;

    float mu = r0 + r1;
    #pragma unroll
    for (int o = 1; o < 64; o <<= 1) mu += __shfl_xor(mu, o);
    mu *= (1.f / 128.f);
    float e0 = r0 - mu, e1 = r1 - mu;
    float var = e0 * e0 + e1 * e1;
    #pragma unroll
    for (int o = 1; o < 64; o <<= 1) var += __shfl_xor(var, o);
    var *= (1.f / 128.f);
    float inv = rsqrtf(var + 1e-5f);

    float y0 = e0 * inv * gamma[j0] + beta[j0];
    float y1 = e1 * inv * gamma[j1] + beta[j1];
    float al = pa[0];
    out[(size_t)n * 128 + j0] = (y0 > 0.f) ? y0 : al * y0;
    out[(size_t)n * 128 + j1] = (y1 > 0.f) ? y1 : al * y1;
}

// ============================================================
extern "C" void kernel_launch(void* const* d_in, const int* in_sizes, int n_in,
                              void* d_out, int out_size, void* d_ws, size_t ws_size,
                              hipStream_t stream) {
    const float* feat  = (const float*)d_in[0];
    const int*   src   = (const int*)d_in[1];
    const int*   dst   = (const int*)d_in[2];
    const float* Wq    = (const float*)d_in[3];
    const float* bq    = (const float*)d_in[4];
    const float* Wk    = (const float*)d_in[5];
    const float* bk    = (const float*)d_in[6];
    const float* Wv    = (const float*)d_in[7];
    const float* bv    = (const float*)d_in[8];
    const float* Wsk   = (const float*)d_in[9];
    const float* bsk   = (const float*)d_in[10];
    const float* Wg    = (const float*)d_in[11];
    const float* bg    = (const float*)d_in[12];
    const float* gamma = (const float*)d_in[13];
    const float* beta  = (const float*)d_in[14];
    const float* pa    = (const float*)d_in[15];
    float* out = (float*)d_out;

    char* ws = (char*)d_ws;
    const size_t NB = (size_t)N_NODES * 128 * 4;   // 51.2 MB
    float*    q   = (float*)(ws);
    float*    k   = (float*)(ws + NB);
    float*    v   = (float*)(ws + 2 * NB);
    float*    sk  = (float*)(ws + 3 * NB);
    float*    a   = (float*)(ws + 4 * NB);                         // E*4 f32
    unsigned* m   = (unsigned*)(ws + 4 * NB + (size_t)N_EDGES * 16);
    float*    den = (float*)(ws + 4 * NB + (size_t)N_EDGES * 16 + (size_t)N_NODES * 16);

    hipMemsetAsync(m,   0, (size_t)N_NODES * 16, stream);
    hipMemsetAsync(den, 0, (size_t)N_NODES * 16, stream);
    hipMemsetAsync(out, 0, (size_t)N_NODES * 128 * 4, stream);  // aggu accumulator

    gemm_proj<<<dim3(782, 4), 256, 0, stream>>>(feat, Wq, bq, Wk, bk, Wv, bv, Wsk, bsk,
                                                q, k, v, sk);
    edge_scores<<<((size_t)N_EDGES * 32 + 255) / 256, 256, 0, stream>>>(q, k, src, dst, a, m);
    edge_accum<<<((size_t)N_EDGES * 32 + 255) / 256, 256, 0, stream>>>(a, m, v, src, dst, den, out);
    finalize<<<(N_NODES + 3) / 4, 256, 0, stream>>>(den, sk, Wg, bg, gamma, beta, pa, out);
}

// Round 3
// 596.078 us; speedup vs baseline: 5.3739x; 5.3739x over previous
//
#include <hip/hip_runtime.h>
#include <math.h>

#define N_NODES 100000
#define N_EDGES 1600000
#define NBLK_SCAN 391   // ceil(100000/256)
// IN=128, HD=128, H=4, D=32

// ============================================================
// Kernel 1: fused 4-way projection GEMM
//   C[M=100000, 128] = feat[M,128] @ W[128,128] + b, for W in {Wq,Wk,Wv,Wskip}
// ============================================================
__global__ __launch_bounds__(256) void gemm_proj(
    const float* __restrict__ feat,
    const float* __restrict__ Wq, const float* __restrict__ bq,
    const float* __restrict__ Wk, const float* __restrict__ bk,
    const float* __restrict__ Wv, const float* __restrict__ bv,
    const float* __restrict__ Ws, const float* __restrict__ bs,
    float* __restrict__ qo, float* __restrict__ ko,
    float* __restrict__ vo, float* __restrict__ so)
{
    __shared__ float As[16][128];   // [kk][row]
    __shared__ float Bs[16][128];   // [kk][col]

    const int m0 = blockIdx.x * 128;
    const int w  = blockIdx.y;
    const float* W    = (w == 0) ? Wq : (w == 1) ? Wk : (w == 2) ? Wv : Ws;
    const float* bias = (w == 0) ? bq : (w == 1) ? bk : (w == 2) ? bv : bs;
    float* out        = (w == 0) ? qo : (w == 1) ? ko : (w == 2) ? vo : so;

    const int t  = threadIdx.x;
    const int tx = t & 15;
    const int ty = t >> 4;

    float acc[8][8];
    #pragma unroll
    for (int i = 0; i < 8; i++)
        #pragma unroll
        for (int j = 0; j < 8; j++) acc[i][j] = 0.f;

    const int lm = t >> 1;
    const int lk = (t & 1) * 8;
    const int wk = t >> 4;
    const int wn = (t & 15) * 8;

    for (int k0 = 0; k0 < 128; k0 += 16) {
        int row = m0 + lm;
        int rc  = row < N_NODES ? row : (N_NODES - 1);
        const float4* fr = (const float4*)(feat + (size_t)rc * 128 + k0 + lk);
        float4 f0 = fr[0];
        float4 f1 = fr[1];
        As[lk + 0][lm] = f0.x; As[lk + 1][lm] = f0.y;
        As[lk + 2][lm] = f0.z; As[lk + 3][lm] = f0.w;
        As[lk + 4][lm] = f1.x; As[lk + 5][lm] = f1.y;
        As[lk + 6][lm] = f1.z; As[lk + 7][lm] = f1.w;

        const float4* wr = (const float4*)(W + (size_t)(k0 + wk) * 128 + wn);
        *(float4*)&Bs[wk][wn]     = wr[0];
        *(float4*)&Bs[wk][wn + 4] = wr[1];

        __syncthreads();

        #pragma unroll
        for (int kk = 0; kk < 16; kk++) {
            float4 a0 = *(const float4*)&As[kk][ty * 8];
            float4 a1 = *(const float4*)&As[kk][ty * 8 + 4];
            float4 b0 = *(const float4*)&Bs[kk][tx * 8];
            float4 b1 = *(const float4*)&Bs[kk][tx * 8 + 4];
            float av[8] = {a0.x, a0.y, a0.z, a0.w, a1.x, a1.y, a1.z, a1.w};
            float bw[8] = {b0.x, b0.y, b0.z, b0.w, b1.x, b1.y, b1.z, b1.w};
            #pragma unroll
            for (int i = 0; i < 8; i++)
                #pragma unroll
                for (int j = 0; j < 8; j++)
                    acc[i][j] += av[i] * bw[j];
        }
        __syncthreads();
    }

    float bvv[8];
    #pragma unroll
    for (int j = 0; j < 8; j++) bvv[j] = bias[tx * 8 + j];

    #pragma unroll
    for (int i = 0; i < 8; i++) {
        int row = m0 + ty * 8 + i;
        if (row < N_NODES) {
            float4 r0, r1;
            r0.x = acc[i][0] + bvv[0]; r0.y = acc[i][1] + bvv[1];
            r0.z = acc[i][2] + bvv[2]; r0.w = acc[i][3] + bvv[3];
            r1.x = acc[i][4] + bvv[4]; r1.y = acc[i][5] + bvv[5];
            r1.z = acc[i][6] + bvv[6]; r1.w = acc[i][7] + bvv[7];
            float* op = out + (size_t)row * 128 + tx * 8;
            *(float4*)op       = r0;
            *(float4*)(op + 4) = r1;
        }
    }
}

// ============================================================
// CSR construction: histogram -> scan -> scatter
// ============================================================
__global__ __launch_bounds__(256) void hist_kernel(
    const int* __restrict__ dst, int* __restrict__ counts)
{
    int e = blockIdx.x * 256 + threadIdx.x;
    if (e < N_EDGES) atomicAdd(&counts[dst[e]], 1);
}

// per-block exclusive scan of 256 elements; writes block sums
__global__ __launch_bounds__(256) void scan_block(
    const int* __restrict__ counts, int* __restrict__ offs, int* __restrict__ bsums)
{
    __shared__ int s[256];
    int i = blockIdx.x * 256 + threadIdx.x;
    int x = (i < N_NODES) ? counts[i] : 0;
    s[threadIdx.x] = x;
    __syncthreads();
    #pragma unroll
    for (int o = 1; o < 256; o <<= 1) {
        int t = (threadIdx.x >= o) ? s[threadIdx.x - o] : 0;
        __syncthreads();
        s[threadIdx.x] += t;
        __syncthreads();
    }
    if (i < N_NODES) offs[i] = s[threadIdx.x] - x;   // exclusive
    if (threadIdx.x == 255) bsums[blockIdx.x] = s[255];
}

// single block scans NBLK_SCAN block sums (exclusive)
__global__ __launch_bounds__(512) void scan_sums(
    int* __restrict__ bsums, int* __restrict__ bscan)
{
    __shared__ int s[512];
    int i = threadIdx.x;
    int x = (i < NBLK_SCAN) ? bsums[i] : 0;
    s[i] = x;
    __syncthreads();
    #pragma unroll
    for (int o = 1; o < 512; o <<= 1) {
        int t = (i >= o) ? s[i - o] : 0;
        __syncthreads();
        s[i] += t;
        __syncthreads();
    }
    if (i < NBLK_SCAN) bscan[i] = s[i] - x;   // exclusive
}

__global__ __launch_bounds__(256) void add_back(
    int* __restrict__ offs, const int* __restrict__ bscan)
{
    int i = blockIdx.x * 256 + threadIdx.x;
    if (i < N_NODES) offs[i] += bscan[blockIdx.x];
}

__global__ __launch_bounds__(256) void scatter_kernel(
    const int* __restrict__ src, const int* __restrict__ dst,
    const int* __restrict__ offs, int* __restrict__ cursor,
    int* __restrict__ sorted_src)
{
    int e = blockIdx.x * 256 + threadIdx.x;
    if (e >= N_EDGES) return;
    int dN = dst[e];
    int pos = offs[dN] + atomicAdd(&cursor[dN], 1);
    sorted_src[pos] = src[e];
}

// ============================================================
// Kernel 3: fused dst-centric aggregation + gate + LN + PReLU
//   one wave per node; lane l owns output elements l and l+64
//   online softmax over incoming edges, all in registers
// ============================================================
__global__ __launch_bounds__(256) void node_fused(
    const float* __restrict__ q, const float* __restrict__ k,
    const float* __restrict__ v, const float* __restrict__ skip,
    const int* __restrict__ offs, const int* __restrict__ sorted_src,
    const float* __restrict__ wg, const float* __restrict__ bg,
    const float* __restrict__ gamma, const float* __restrict__ beta,
    const float* __restrict__ pa, float* __restrict__ out)
{
    int wid = threadIdx.x >> 6;
    int l   = threadIdx.x & 63;
    int n = blockIdx.x * 4 + wid;
    if (n >= N_NODES) return;

    int start = offs[n];
    int end   = (n + 1 < N_NODES) ? offs[n + 1] : N_EDGES;

    float k0 = k[(size_t)n * 128 + l];
    float k1 = k[(size_t)n * 128 + l + 64];

    float m0 = -1e30f, m1 = -1e30f;
    float den0 = 0.f, den1 = 0.f;
    float a0 = 0.f, a1 = 0.f;
    const float isd = 0.17677669529663687f;   // 1/sqrt(32)

    for (int idx = start; idx < end; ++idx) {
        int sN = sorted_src[idx];
        const float* qr = q + (size_t)sN * 128;
        const float* vr = v + (size_t)sN * 128;
        float q0 = qr[l], q1 = qr[l + 64];
        float v0 = vr[l], v1 = vr[l + 64];
        float p0 = q0 * k0, p1 = q1 * k1;
        // half-wave reduce (heads are 32-element segments; lanes 0-31 hold
        // heads {0,2}, lanes 32-63 hold heads {1,3})
        #pragma unroll
        for (int o = 1; o <= 16; o <<= 1) {
            p0 += __shfl_xor(p0, o);
            p1 += __shfl_xor(p1, o);
        }
        float s0 = p0 * isd, s1 = p1 * isd;
        float nm0 = fmaxf(m0, s0), nm1 = fmaxf(m1, s1);
        float sc0 = __expf(m0 - nm0), sc1 = __expf(m1 - nm1);
        float e0  = __expf(s0 - nm0), e1  = __expf(s1 - nm1);
        den0 = den0 * sc0 + e0;  den1 = den1 * sc1 + e1;
        a0   = a0 * sc0 + e0 * v0;  a1 = a1 * sc1 + e1 * v1;
        m0 = nm0; m1 = nm1;
    }

    float r0 = a0 / den0;
    float r1 = a1 / den1;
    float s0 = skip[(size_t)n * 128 + l];
    float s1 = skip[(size_t)n * 128 + l + 64];

    // gate
    float gs = s0 * wg[l]        + r0 * wg[128 + l]      + (s0 - r0) * wg[256 + l]
             + s1 * wg[l + 64]   + r1 * wg[128 + l + 64] + (s1 - r1) * wg[256 + l + 64];
    #pragma unroll
    for (int o = 1; o < 64; o <<= 1) gs += __shfl_xor(gs, o);
    float g = 1.f / (1.f + __expf(-(gs + bg[0])));

    r0 = g * s0 + (1.f - g) * r0;
    r1 = g * s1 + (1.f - g) * r1;

    // LayerNorm over 128
    float mu = r0 + r1;
    #pragma unroll
    for (int o = 1; o < 64; o <<= 1) mu += __shfl_xor(mu, o);
    mu *= (1.f / 128.f);
    float e0 = r0 - mu, e1 = r1 - mu;
    float var = e0 * e0 + e1 * e1;
    #pragma unroll
    for (int o = 1; o < 64; o <<= 1) var += __shfl_xor(var, o);
    var *= (1.f / 128.f);
    float inv = rsqrtf(var + 1e-5f);

    float y0 = e0 * inv * gamma[l] + beta[l];
    float y1 = e1 * inv * gamma[l + 64] + beta[l + 64];
    float al = pa[0];
    out[(size_t)n * 128 + l]      = (y0 > 0.f) ? y0 : al * y0;
    out[(size_t)n * 128 + l + 64] = (y1 > 0.f) ? y1 : al * y1;
}

// ============================================================
extern "C" void kernel_launch(void* const* d_in, const int* in_sizes, int n_in,
                              void* d_out, int out_size, void* d_ws, size_t ws_size,
                              hipStream_t stream) {
    const float* feat  = (const float*)d_in[0];
    const int*   src   = (const int*)d_in[1];
    const int*   dst   = (const int*)d_in[2];
    const float* Wq    = (const float*)d_in[3];
    const float* bq    = (const float*)d_in[4];
    const float* Wk    = (const float*)d_in[5];
    const float* bk    = (const float*)d_in[6];
    const float* Wv    = (const float*)d_in[7];
    const float* bv    = (const float*)d_in[8];
    const float* Wsk   = (const float*)d_in[9];
    const float* bsk   = (const float*)d_in[10];
    const float* Wg    = (const float*)d_in[11];
    const float* bg    = (const float*)d_in[12];
    const float* gamma = (const float*)d_in[13];
    const float* beta  = (const float*)d_in[14];
    const float* pa    = (const float*)d_in[15];
    float* out = (float*)d_out;

    char* ws = (char*)d_ws;
    const size_t NB = (size_t)N_NODES * 128 * 4;   // 51.2 MB
    float* q  = (float*)(ws);
    float* k  = (float*)(ws + NB);
    float* v  = (float*)(ws + 2 * NB);
    float* sk = (float*)(ws + 3 * NB);
    char* p = ws + 4 * NB;
    int* sorted_src = (int*)p;            p += (size_t)N_EDGES * 4;
    int* counts     = (int*)p;            p += (size_t)N_NODES * 4;
    int* offs       = (int*)p;            p += (size_t)N_NODES * 4;
    int* cursor     = (int*)p;            p += (size_t)N_NODES * 4;
    int* bsums      = (int*)p;            p += 4096;
    int* bscan      = (int*)p;            p += 4096;

    hipMemsetAsync(counts, 0, (size_t)N_NODES * 4, stream);
    hipMemsetAsync(cursor, 0, (size_t)N_NODES * 4, stream);

    gemm_proj<<<dim3(782, 4), 256, 0, stream>>>(feat, Wq, bq, Wk, bk, Wv, bv, Wsk, bsk,
                                                q, k, v, sk);
    hist_kernel<<<(N_EDGES + 255) / 256, 256, 0, stream>>>(dst, counts);
    scan_block<<<NBLK_SCAN, 256, 0, stream>>>(counts, offs, bsums);
    scan_sums<<<1, 512, 0, stream>>>(bsums, bscan);
    add_back<<<NBLK_SCAN, 256, 0, stream>>>(offs, bscan);
    scatter_kernel<<<(N_EDGES + 255) / 256, 256, 0, stream>>>(src, dst, offs, cursor, sorted_src);
    node_fused<<<(N_NODES + 3) / 4, 256, 0, stream>>>(q, k, v, sk, offs, sorted_src,
                                                      Wg, bg, gamma, beta, pa, out);
}

// Round 4
// 421.371 us; speedup vs baseline: 7.6020x; 1.4146x over previous
//
#include <hip/hip_runtime.h>
#include <math.h>

#define N_NODES 100000
#define N_EDGES 1600000
#define NBLK_SCAN 391   // ceil(100000/256)
// IN=128, HD=128, H=4, D=32

typedef __attribute__((ext_vector_type(8))) short bf16x8;
typedef __attribute__((ext_vector_type(4))) float f32x4;

__device__ __forceinline__ unsigned short f2bf(float x) {
    unsigned u = __float_as_uint(x);
    unsigned r = (u + 0x7fffu + ((u >> 16) & 1u)) >> 16;   // RNE
    return (unsigned short)r;
}
__device__ __forceinline__ float bflo(unsigned u) { return __uint_as_float(u << 16); }
__device__ __forceinline__ float bfhi(unsigned u) { return __uint_as_float(u & 0xffff0000u); }

// ============================================================
// feat fp32 -> bf16
// ============================================================
__global__ __launch_bounds__(256) void convert_feat(
    const float* __restrict__ f, unsigned short* __restrict__ fb)
{
    int i = blockIdx.x * 256 + threadIdx.x;          // float4 index
    if (i >= N_NODES * 32) return;                    // 12.8M/4
    float4 x = ((const float4*)f)[i];
    ushort4 o;
    o.x = f2bf(x.x); o.y = f2bf(x.y); o.z = f2bf(x.z); o.w = f2bf(x.w);
    ((ushort4*)fb)[i] = o;
}

// ============================================================
// W[mat][k][c] fp32 -> Wtb[mat][c][k] bf16 (transposed for MFMA B-frags)
// ============================================================
__global__ __launch_bounds__(128) void convert_w(
    const float* __restrict__ Wq, const float* __restrict__ Wk,
    const float* __restrict__ Wv, const float* __restrict__ Ws,
    unsigned short* __restrict__ Wtb)
{
    int c = blockIdx.x;          // 0..127 (output col)
    int m = blockIdx.y;          // 0..3
    int k = threadIdx.x;         // 0..127
    const float* W = (m == 0) ? Wq : (m == 1) ? Wk : (m == 2) ? Wv : Ws;
    Wtb[((size_t)m * 128 + c) * 128 + k] = f2bf(W[(size_t)k * 128 + c]);
}

// ============================================================
// MFMA GEMM: out[mat][100000,128] = feat @ W[mat] + b[mat]
//   grid (782, 4), 256 thr = 4 waves; wave w: rows m0+w*32..+32, cols 0..128
//   no LDS: A-frags direct from featb, B-frags direct from Wtb (L1/L2-hot)
// ============================================================
__global__ __launch_bounds__(256) void gemm_mfma(
    const unsigned short* __restrict__ featb, const unsigned short* __restrict__ Wtb,
    const float* __restrict__ bq, const float* __restrict__ bk,
    const float* __restrict__ bv, const float* __restrict__ bs,
    unsigned short* __restrict__ qb, unsigned short* __restrict__ kb,
    unsigned short* __restrict__ vb, float* __restrict__ sk)
{
    const int mat = blockIdx.y;
    const int m0  = blockIdx.x * 128;
    const int w   = threadIdx.x >> 6;
    const int l   = threadIdx.x & 63;
    const int lr  = l & 15;      // row/col within fragment
    const int lg  = l >> 4;      // k-group
    const int r_base = m0 + w * 32;
    const float* bias = (mat == 0) ? bq : (mat == 1) ? bk : (mat == 2) ? bv : bs;

    f32x4 acc[2][8];
    #pragma unroll
    for (int i = 0; i < 2; i++)
        #pragma unroll
        for (int j = 0; j < 8; j++) acc[i][j] = (f32x4){0.f, 0.f, 0.f, 0.f};

    #pragma unroll
    for (int ks = 0; ks < 4; ks++) {
        const int k0 = ks * 32 + lg * 8;
        bf16x8 a[2], b[8];
        #pragma unroll
        for (int rf = 0; rf < 2; rf++) {
            int row = r_base + rf * 16 + lr;
            row = (row < N_NODES) ? row : (N_NODES - 1);
            a[rf] = *(const bf16x8*)(featb + (size_t)row * 128 + k0);
        }
        #pragma unroll
        for (int cf = 0; cf < 8; cf++) {
            int col = cf * 16 + lr;
            b[cf] = *(const bf16x8*)(Wtb + ((size_t)mat * 128 + col) * 128 + k0);
        }
        #pragma unroll
        for (int rf = 0; rf < 2; rf++)
            #pragma unroll
            for (int cf = 0; cf < 8; cf++)
                acc[rf][cf] = __builtin_amdgcn_mfma_f32_16x16x32_bf16(
                    a[rf], b[cf], acc[rf][cf], 0, 0, 0);
    }

    // epilogue: C/D layout col = lane&15, row = (lane>>4)*4 + reg  [m89]
    #pragma unroll
    for (int rf = 0; rf < 2; rf++) {
        #pragma unroll
        for (int cf = 0; cf < 8; cf++) {
            int col = cf * 16 + lr;
            float bv_ = bias[col];
            #pragma unroll
            for (int reg = 0; reg < 4; reg++) {
                int row = r_base + rf * 16 + lg * 4 + reg;
                if (row < N_NODES) {
                    float val = acc[rf][cf][reg] + bv_;
                    if (mat == 3) {
                        sk[(size_t)row * 128 + col] = val;
                    } else {
                        unsigned short* o = (mat == 0) ? qb : (mat == 1) ? kb : vb;
                        o[(size_t)row * 128 + col] = f2bf(val);
                    }
                }
            }
        }
    }
}

// ============================================================
// CSR construction: histogram -> scan -> scatter
// ============================================================
__global__ __launch_bounds__(256) void hist_kernel(
    const int* __restrict__ dst, int* __restrict__ counts)
{
    int e = blockIdx.x * 256 + threadIdx.x;
    if (e < N_EDGES) atomicAdd(&counts[dst[e]], 1);
}

__global__ __launch_bounds__(256) void scan_block(
    const int* __restrict__ counts, int* __restrict__ offs, int* __restrict__ bsums)
{
    __shared__ int s[256];
    int i = blockIdx.x * 256 + threadIdx.x;
    int x = (i < N_NODES) ? counts[i] : 0;
    s[threadIdx.x] = x;
    __syncthreads();
    #pragma unroll
    for (int o = 1; o < 256; o <<= 1) {
        int t = (threadIdx.x >= o) ? s[threadIdx.x - o] : 0;
        __syncthreads();
        s[threadIdx.x] += t;
        __syncthreads();
    }
    if (i < N_NODES) offs[i] = s[threadIdx.x] - x;
    if (threadIdx.x == 255) bsums[blockIdx.x] = s[255];
}

__global__ __launch_bounds__(512) void scan_sums(
    int* __restrict__ bsums, int* __restrict__ bscan)
{
    __shared__ int s[512];
    int i = threadIdx.x;
    int x = (i < NBLK_SCAN) ? bsums[i] : 0;
    s[i] = x;
    __syncthreads();
    #pragma unroll
    for (int o = 1; o < 512; o <<= 1) {
        int t = (i >= o) ? s[i - o] : 0;
        __syncthreads();
        s[i] += t;
        __syncthreads();
    }
    if (i < NBLK_SCAN) bscan[i] = s[i] - x;
}

__global__ __launch_bounds__(256) void add_back(
    int* __restrict__ offs, const int* __restrict__ bscan)
{
    int i = blockIdx.x * 256 + threadIdx.x;
    if (i < N_NODES) offs[i] += bscan[blockIdx.x];
}

__global__ __launch_bounds__(256) void scatter_kernel(
    const int* __restrict__ src, const int* __restrict__ dst,
    const int* __restrict__ offs, int* __restrict__ cursor,
    int* __restrict__ sorted_src)
{
    int e = blockIdx.x * 256 + threadIdx.x;
    if (e >= N_EDGES) return;
    int dN = dst[e];
    int pos = offs[dN] + atomicAdd(&cursor[dN], 1);
    sorted_src[pos] = src[e];
}

// ============================================================
// fused dst-centric aggregation + gate + LN + PReLU
//   one wave per node; lane l owns elements 2l, 2l+1 (same head = l>>4)
//   bf16 q/k/v gathers, online softmax, 2-edge unroll
// ============================================================
__global__ __launch_bounds__(256) void node_fused(
    const unsigned short* __restrict__ qb, const unsigned short* __restrict__ kb,
    const unsigned short* __restrict__ vb, const float* __restrict__ sk,
    const int* __restrict__ offs, const int* __restrict__ sorted_src,
    const float* __restrict__ wg, const float* __restrict__ bg,
    const float* __restrict__ gamma, const float* __restrict__ beta,
    const float* __restrict__ pa, float* __restrict__ out)
{
    int wid = threadIdx.x >> 6;
    int l   = threadIdx.x & 63;
    int n = blockIdx.x * 4 + wid;
    if (n >= N_NODES) return;

    int start = offs[n];
    int end   = (n + 1 < N_NODES) ? offs[n + 1] : N_EDGES;

    const unsigned* qu = (const unsigned*)qb;
    const unsigned* vu = (const unsigned*)vb;
    unsigned kp = ((const unsigned*)kb)[(size_t)n * 64 + l];
    float k0 = bflo(kp), k1 = bfhi(kp);

    float m = -1e30f, den = 0.f, a0 = 0.f, a1 = 0.f;
    const float isd = 0.17677669529663687f;   // 1/sqrt(32)

    int idx = start;
    for (; idx + 1 < end; idx += 2) {
        int s1 = sorted_src[idx], s2 = sorted_src[idx + 1];
        unsigned qp1 = qu[(size_t)s1 * 64 + l];
        unsigned vp1 = vu[(size_t)s1 * 64 + l];
        unsigned qp2 = qu[(size_t)s2 * 64 + l];
        unsigned vp2 = vu[(size_t)s2 * 64 + l];
        float d1 = bflo(qp1) * k0 + bfhi(qp1) * k1;
        float d2 = bflo(qp2) * k0 + bfhi(qp2) * k1;
        #pragma unroll
        for (int o = 1; o <= 8; o <<= 1) {
            d1 += __shfl_xor(d1, o);
            d2 += __shfl_xor(d2, o);
        }
        d1 *= isd; d2 *= isd;
        float nm = fmaxf(m, fmaxf(d1, d2));
        float sc = __expf(m - nm);
        float e1 = __expf(d1 - nm);
        float e2 = __expf(d2 - nm);
        den = den * sc + e1 + e2;
        a0  = a0 * sc + e1 * bflo(vp1) + e2 * bflo(vp2);
        a1  = a1 * sc + e1 * bfhi(vp1) + e2 * bfhi(vp2);
        m = nm;
    }
    if (idx < end) {
        int s1 = sorted_src[idx];
        unsigned qp1 = qu[(size_t)s1 * 64 + l];
        unsigned vp1 = vu[(size_t)s1 * 64 + l];
        float d1 = bflo(qp1) * k0 + bfhi(qp1) * k1;
        #pragma unroll
        for (int o = 1; o <= 8; o <<= 1) d1 += __shfl_xor(d1, o);
        d1 *= isd;
        float nm = fmaxf(m, d1);
        float sc = __expf(m - nm);
        float e1 = __expf(d1 - nm);
        den = den * sc + e1;
        a0  = a0 * sc + e1 * bflo(vp1);
        a1  = a1 * sc + e1 * bfhi(vp1);
    }

    float r0 = a0 / den;
    float r1 = a1 / den;
    float2 sp = ((const float2*)sk)[(size_t)n * 64 + l];
    float s0 = sp.x, s1f = sp.y;

    // gate
    float2 w0 = ((const float2*)wg)[l];
    float2 w1 = ((const float2*)(wg + 128))[l];
    float2 w2 = ((const float2*)(wg + 256))[l];
    float gs = s0 * w0.x + r0 * w1.x + (s0 - r0) * w2.x
             + s1f * w0.y + r1 * w1.y + (s1f - r1) * w2.y;
    #pragma unroll
    for (int o = 1; o < 64; o <<= 1) gs += __shfl_xor(gs, o);
    float g = 1.f / (1.f + __expf(-(gs + bg[0])));

    r0 = g * s0 + (1.f - g) * r0;
    r1 = g * s1f + (1.f - g) * r1;

    // LayerNorm over 128
    float mu = r0 + r1;
    #pragma unroll
    for (int o = 1; o < 64; o <<= 1) mu += __shfl_xor(mu, o);
    mu *= (1.f / 128.f);
    float e0 = r0 - mu, e1 = r1 - mu;
    float var = e0 * e0 + e1 * e1;
    #pragma unroll
    for (int o = 1; o < 64; o <<= 1) var += __shfl_xor(var, o);
    var *= (1.f / 128.f);
    float inv = rsqrtf(var + 1e-5f);

    float2 gm = ((const float2*)gamma)[l];
    float2 bt = ((const float2*)beta)[l];
    float y0 = e0 * inv * gm.x + bt.x;
    float y1 = e1 * inv * gm.y + bt.y;
    float al = pa[0];
    float2 yo;
    yo.x = (y0 > 0.f) ? y0 : al * y0;
    yo.y = (y1 > 0.f) ? y1 : al * y1;
    ((float2*)out)[(size_t)n * 64 + l] = yo;
}

// ============================================================
extern "C" void kernel_launch(void* const* d_in, const int* in_sizes, int n_in,
                              void* d_out, int out_size, void* d_ws, size_t ws_size,
                              hipStream_t stream) {
    const float* feat  = (const float*)d_in[0];
    const int*   src   = (const int*)d_in[1];
    const int*   dst   = (const int*)d_in[2];
    const float* Wq    = (const float*)d_in[3];
    const float* bq    = (const float*)d_in[4];
    const float* Wk    = (const float*)d_in[5];
    const float* bk    = (const float*)d_in[6];
    const float* Wv    = (const float*)d_in[7];
    const float* bv    = (const float*)d_in[8];
    const float* Wsk   = (const float*)d_in[9];
    const float* bsk   = (const float*)d_in[10];
    const float* Wg    = (const float*)d_in[11];
    const float* bg    = (const float*)d_in[12];
    const float* gamma = (const float*)d_in[13];
    const float* beta  = (const float*)d_in[14];
    const float* pa    = (const float*)d_in[15];
    float* out = (float*)d_out;

    char* p = (char*)d_ws;
    const size_t NB2 = (size_t)N_NODES * 128 * 2;   // 25.6 MB bf16 plane
    unsigned short* featb = (unsigned short*)p;  p += NB2;
    unsigned short* qb    = (unsigned short*)p;  p += NB2;
    unsigned short* kb    = (unsigned short*)p;  p += NB2;
    unsigned short* vb    = (unsigned short*)p;  p += NB2;
    float*          sk    = (float*)p;           p += (size_t)N_NODES * 128 * 4;
    unsigned short* Wtb   = (unsigned short*)p;  p += (size_t)4 * 128 * 128 * 2;
    int* sorted_src = (int*)p;  p += (size_t)N_EDGES * 4;
    int* counts     = (int*)p;  p += (size_t)N_NODES * 4;
    int* offs       = (int*)p;  p += (size_t)N_NODES * 4;
    int* cursor     = (int*)p;  p += (size_t)N_NODES * 4;
    int* bsums      = (int*)p;  p += 4096;
    int* bscan      = (int*)p;  p += 4096;

    hipMemsetAsync(counts, 0, (size_t)N_NODES * 4, stream);
    hipMemsetAsync(cursor, 0, (size_t)N_NODES * 4, stream);

    convert_feat<<<(N_NODES * 32 + 255) / 256, 256, 0, stream>>>(feat, featb);
    convert_w<<<dim3(128, 4), 128, 0, stream>>>(Wq, Wk, Wv, Wsk, Wtb);
    gemm_mfma<<<dim3(782, 4), 256, 0, stream>>>(featb, Wtb, bq, bk, bv, bsk,
                                                qb, kb, vb, sk);
    hist_kernel<<<(N_EDGES + 255) / 256, 256, 0, stream>>>(dst, counts);
    scan_block<<<NBLK_SCAN, 256, 0, stream>>>(counts, offs, bsums);
    scan_sums<<<1, 512, 0, stream>>>(bsums, bscan);
    add_back<<<NBLK_SCAN, 256, 0, stream>>>(offs, bscan);
    scatter_kernel<<<(N_EDGES + 255) / 256, 256, 0, stream>>>(src, dst, offs, cursor, sorted_src);
    node_fused<<<(N_NODES + 3) / 4, 256, 0, stream>>>(qb, kb, vb, sk, offs, sorted_src,
                                                      Wg, bg, gamma, beta, pa, out);
}

// Round 5
// 410.591 us; speedup vs baseline: 7.8016x; 1.0263x over previous
//
#include <hip/hip_runtime.h>
#include <math.h>

#define N_NODES 100000
#define N_EDGES 1600000
#define NBLK_SCAN 391   // ceil(100000/256)
// IN=128, HD=128, H=4, D=32

typedef __attribute__((ext_vector_type(8))) short bf16x8;
typedef __attribute__((ext_vector_type(4))) float f32x4;

__device__ __forceinline__ unsigned short f2bf(float x) {
    unsigned u = __float_as_uint(x);
    unsigned r = (u + 0x7fffu + ((u >> 16) & 1u)) >> 16;   // RNE
    return (unsigned short)r;
}
__device__ __forceinline__ float bflo(unsigned u) { return __uint_as_float(u << 16); }
__device__ __forceinline__ float bfhi(unsigned u) { return __uint_as_float(u & 0xffff0000u); }

// ============================================================
// prep: fused [feat->bf16] + [dst histogram] + [W transpose->bf16]
//   blocks 0..12499: convert feat (3.2M float4)
//   blocks 12500..18749: histogram over 1.6M edges
//   blocks 18750..19005: Wtb[m][c][k] = W[m][k][c]  (65536 elems)
// ============================================================
__global__ __launch_bounds__(256) void prep(
    const float* __restrict__ feat, const int* __restrict__ dst,
    const float* __restrict__ Wq, const float* __restrict__ Wk,
    const float* __restrict__ Wv, const float* __restrict__ Ws,
    unsigned short* __restrict__ fb, unsigned short* __restrict__ Wtb,
    int* __restrict__ counts)
{
    int bid = blockIdx.x;
    if (bid < 12500) {
        int i = bid * 256 + threadIdx.x;
        float4 x = ((const float4*)feat)[i];
        ushort4 o;
        o.x = f2bf(x.x); o.y = f2bf(x.y); o.z = f2bf(x.z); o.w = f2bf(x.w);
        ((ushort4*)fb)[i] = o;
    } else if (bid < 18750) {
        int e = (bid - 12500) * 256 + threadIdx.x;
        atomicAdd(&counts[dst[e]], 1);
    } else {
        int j = (bid - 18750) * 256 + threadIdx.x;   // [0, 65536)
        int m = j >> 14;
        int rem = j & 16383;
        int c = rem >> 7;
        int kk = rem & 127;
        const float* W = (m == 0) ? Wq : (m == 1) ? Wk : (m == 2) ? Wv : Ws;
        Wtb[j] = f2bf(W[(size_t)kk * 128 + c]);
    }
}

// ============================================================
// MFMA GEMM: out[mat][100000,128] = feat @ W[mat] + b[mat]
// ============================================================
__global__ __launch_bounds__(256) void gemm_mfma(
    const unsigned short* __restrict__ featb, const unsigned short* __restrict__ Wtb,
    const float* __restrict__ bq, const float* __restrict__ bk,
    const float* __restrict__ bv, const float* __restrict__ bs,
    unsigned short* __restrict__ qb, unsigned short* __restrict__ kb,
    unsigned short* __restrict__ vb, float* __restrict__ sk)
{
    const int mat = blockIdx.y;
    const int m0  = blockIdx.x * 128;
    const int w   = threadIdx.x >> 6;
    const int l   = threadIdx.x & 63;
    const int lr  = l & 15;
    const int lg  = l >> 4;
    const int r_base = m0 + w * 32;
    const float* bias = (mat == 0) ? bq : (mat == 1) ? bk : (mat == 2) ? bv : bs;

    f32x4 acc[2][8];
    #pragma unroll
    for (int i = 0; i < 2; i++)
        #pragma unroll
        for (int j = 0; j < 8; j++) acc[i][j] = (f32x4){0.f, 0.f, 0.f, 0.f};

    #pragma unroll
    for (int ks = 0; ks < 4; ks++) {
        const int k0 = ks * 32 + lg * 8;
        bf16x8 a[2], b[8];
        #pragma unroll
        for (int rf = 0; rf < 2; rf++) {
            int row = r_base + rf * 16 + lr;
            row = (row < N_NODES) ? row : (N_NODES - 1);
            a[rf] = *(const bf16x8*)(featb + (size_t)row * 128 + k0);
        }
        #pragma unroll
        for (int cf = 0; cf < 8; cf++) {
            int col = cf * 16 + lr;
            b[cf] = *(const bf16x8*)(Wtb + ((size_t)mat * 128 + col) * 128 + k0);
        }
        #pragma unroll
        for (int rf = 0; rf < 2; rf++)
            #pragma unroll
            for (int cf = 0; cf < 8; cf++)
                acc[rf][cf] = __builtin_amdgcn_mfma_f32_16x16x32_bf16(
                    a[rf], b[cf], acc[rf][cf], 0, 0, 0);
    }

    #pragma unroll
    for (int rf = 0; rf < 2; rf++) {
        #pragma unroll
        for (int cf = 0; cf < 8; cf++) {
            int col = cf * 16 + lr;
            float bv_ = bias[col];
            #pragma unroll
            for (int reg = 0; reg < 4; reg++) {
                int row = r_base + rf * 16 + lg * 4 + reg;
                if (row < N_NODES) {
                    float val = acc[rf][cf][reg] + bv_;
                    if (mat == 3) {
                        sk[(size_t)row * 128 + col] = val;
                    } else {
                        unsigned short* o = (mat == 0) ? qb : (mat == 1) ? kb : vb;
                        o[(size_t)row * 128 + col] = f2bf(val);
                    }
                }
            }
        }
    }
}

// ============================================================
// CSR: scan + scatter
// ============================================================
__global__ __launch_bounds__(256) void scan_block(
    const int* __restrict__ counts, int* __restrict__ offs, int* __restrict__ bsums)
{
    __shared__ int s[256];
    int i = blockIdx.x * 256 + threadIdx.x;
    int x = (i < N_NODES) ? counts[i] : 0;
    s[threadIdx.x] = x;
    __syncthreads();
    #pragma unroll
    for (int o = 1; o < 256; o <<= 1) {
        int t = (threadIdx.x >= o) ? s[threadIdx.x - o] : 0;
        __syncthreads();
        s[threadIdx.x] += t;
        __syncthreads();
    }
    if (i < N_NODES) offs[i] = s[threadIdx.x] - x;
    if (threadIdx.x == 255) bsums[blockIdx.x] = s[255];
}

__global__ __launch_bounds__(512) void scan_sums(
    int* __restrict__ bsums, int* __restrict__ bscan)
{
    __shared__ int s[512];
    int i = threadIdx.x;
    int x = (i < NBLK_SCAN) ? bsums[i] : 0;
    s[i] = x;
    __syncthreads();
    #pragma unroll
    for (int o = 1; o < 512; o <<= 1) {
        int t = (i >= o) ? s[i - o] : 0;
        __syncthreads();
        s[i] += t;
        __syncthreads();
    }
    if (i < NBLK_SCAN) bscan[i] = s[i] - x;
}

__global__ __launch_bounds__(256) void add_back(
    int* __restrict__ offs, const int* __restrict__ bscan, int* __restrict__ cursor)
{
    int i = blockIdx.x * 256 + threadIdx.x;
    if (i < N_NODES) {
        offs[i] += bscan[blockIdx.x];
        cursor[i] = 0;
    }
}

__global__ __launch_bounds__(256) void scatter_kernel(
    const int* __restrict__ src, const int* __restrict__ dst,
    const int* __restrict__ offs, int* __restrict__ cursor,
    int* __restrict__ sorted_src)
{
    int e = blockIdx.x * 256 + threadIdx.x;
    if (e >= N_EDGES) return;
    int dN = dst[e];
    int pos = offs[dN] + atomicAdd(&cursor[dN], 1);
    sorted_src[pos] = src[e];
}

// ============================================================
// fused dst-centric aggregation + gate + LN + PReLU
//   one wave per node; lane = (half, c): half-wave per edge (2 edges/iter),
//   lane owns elems 4c..4c+3 (head = c>>3, 8 lanes/head -> 3-step reduce)
//   softmax WITHOUT max subtraction (scores bounded ~|2|, exp-safe)
// ============================================================
__global__ __launch_bounds__(256) void node_fused(
    const unsigned short* __restrict__ qb, const unsigned short* __restrict__ kb,
    const unsigned short* __restrict__ vb, const float* __restrict__ sk,
    const int* __restrict__ offs, const int* __restrict__ sorted_src,
    const float* __restrict__ wg, const float* __restrict__ bg,
    const float* __restrict__ gamma, const float* __restrict__ beta,
    const float* __restrict__ pa, float* __restrict__ out)
{
    int wid  = threadIdx.x >> 6;
    int l    = threadIdx.x & 63;
    int half = l >> 5;
    int c    = l & 31;
    int n = blockIdx.x * 4 + wid;
    if (n >= N_NODES) return;

    int start = offs[n];
    int end   = (n + 1 < N_NODES) ? offs[n + 1] : N_EDGES;

    const uint2* qu = (const uint2*)qb;
    const uint2* vu = (const uint2*)vb;
    uint2 kp = ((const uint2*)kb)[(size_t)n * 32 + c];
    float k0 = bflo(kp.x), k1 = bfhi(kp.x), k2 = bflo(kp.y), k3 = bfhi(kp.y);

    float den = 0.f, a0 = 0.f, a1 = 0.f, a2 = 0.f, a3 = 0.f;
    const float C = 0.25503483f;   // (1/sqrt(32)) * log2(e)

    int idx = start;
    #pragma unroll 2
    for (; idx + 1 < end; idx += 2) {
        int s = sorted_src[idx + half];
        uint2 qp = qu[(size_t)s * 32 + c];
        uint2 vp = vu[(size_t)s * 32 + c];
        float d = bflo(qp.x) * k0 + bfhi(qp.x) * k1
                + bflo(qp.y) * k2 + bfhi(qp.y) * k3;
        d += __shfl_xor(d, 1);
        d += __shfl_xor(d, 2);
        d += __shfl_xor(d, 4);
        float e = __builtin_amdgcn_exp2f(d * C);
        den += e;
        a0 += e * bflo(vp.x); a1 += e * bfhi(vp.x);
        a2 += e * bflo(vp.y); a3 += e * bfhi(vp.y);
    }
    if (idx < end) {                       // 1 edge left; half 1 idle
        int s = sorted_src[idx];           // both halves load the valid one
        uint2 qp = qu[(size_t)s * 32 + c];
        uint2 vp = vu[(size_t)s * 32 + c];
        float d = bflo(qp.x) * k0 + bfhi(qp.x) * k1
                + bflo(qp.y) * k2 + bfhi(qp.y) * k3;
        d += __shfl_xor(d, 1);
        d += __shfl_xor(d, 2);
        d += __shfl_xor(d, 4);
        float e = (half == 0) ? __builtin_amdgcn_exp2f(d * C) : 0.f;
        den += e;
        a0 += e * bflo(vp.x); a1 += e * bfhi(vp.x);
        a2 += e * bflo(vp.y); a3 += e * bfhi(vp.y);
    }

    // merge the two halves
    den += __shfl_xor(den, 32);
    a0 += __shfl_xor(a0, 32); a1 += __shfl_xor(a1, 32);
    a2 += __shfl_xor(a2, 32); a3 += __shfl_xor(a3, 32);

    float rd = 1.f / den;
    float r0 = a0 * rd, r1 = a1 * rd, r2 = a2 * rd, r3 = a3 * rd;

    float4 sp = ((const float4*)sk)[(size_t)n * 32 + c];
    float4 w0 = ((const float4*)wg)[c];
    float4 w1 = ((const float4*)wg)[32 + c];
    float4 w2 = ((const float4*)wg)[64 + c];

    float gs = sp.x * w0.x + r0 * w1.x + (sp.x - r0) * w2.x
             + sp.y * w0.y + r1 * w1.y + (sp.y - r1) * w2.y
             + sp.z * w0.z + r2 * w1.z + (sp.z - r2) * w2.z
             + sp.w * w0.w + r3 * w1.w + (sp.w - r3) * w2.w;
    #pragma unroll
    for (int o = 1; o < 32; o <<= 1) gs += __shfl_xor(gs, o);
    float g = 1.f / (1.f + __builtin_amdgcn_exp2f(-(gs + bg[0]) * 1.4426950408889634f));

    r0 = g * sp.x + (1.f - g) * r0;
    r1 = g * sp.y + (1.f - g) * r1;
    r2 = g * sp.z + (1.f - g) * r2;
    r3 = g * sp.w + (1.f - g) * r3;

    float mu = r0 + r1 + r2 + r3;
    #pragma unroll
    for (int o = 1; o < 32; o <<= 1) mu += __shfl_xor(mu, o);
    mu *= (1.f / 128.f);
    float e0 = r0 - mu, e1 = r1 - mu, e2 = r2 - mu, e3 = r3 - mu;
    float var = e0 * e0 + e1 * e1 + e2 * e2 + e3 * e3;
    #pragma unroll
    for (int o = 1; o < 32; o <<= 1) var += __shfl_xor(var, o);
    var *= (1.f / 128.f);
    float inv = rsqrtf(var + 1e-5f);

    if (half == 0) {
        float4 gm = ((const float4*)gamma)[c];
        float4 bt = ((const float4*)beta)[c];
        float al = pa[0];
        float y0 = e0 * inv * gm.x + bt.x;
        float y1 = e1 * inv * gm.y + bt.y;
        float y2 = e2 * inv * gm.z + bt.z;
        float y3 = e3 * inv * gm.w + bt.w;
        float4 yo;
        yo.x = (y0 > 0.f) ? y0 : al * y0;
        yo.y = (y1 > 0.f) ? y1 : al * y1;
        yo.z = (y2 > 0.f) ? y2 : al * y2;
        yo.w = (y3 > 0.f) ? y3 : al * y3;
        ((float4*)out)[(size_t)n * 32 + c] = yo;
    }
}

// ============================================================
extern "C" void kernel_launch(void* const* d_in, const int* in_sizes, int n_in,
                              void* d_out, int out_size, void* d_ws, size_t ws_size,
                              hipStream_t stream) {
    const float* feat  = (const float*)d_in[0];
    const int*   src   = (const int*)d_in[1];
    const int*   dst   = (const int*)d_in[2];
    const float* Wq    = (const float*)d_in[3];
    const float* bq    = (const float*)d_in[4];
    const float* Wk    = (const float*)d_in[5];
    const float* bk    = (const float*)d_in[6];
    const float* Wv    = (const float*)d_in[7];
    const float* bv    = (const float*)d_in[8];
    const float* Wsk   = (const float*)d_in[9];
    const float* bsk   = (const float*)d_in[10];
    const float* Wg    = (const float*)d_in[11];
    const float* bg    = (const float*)d_in[12];
    const float* gamma = (const float*)d_in[13];
    const float* beta  = (const float*)d_in[14];
    const float* pa    = (const float*)d_in[15];
    float* out = (float*)d_out;

    char* p = (char*)d_ws;
    const size_t NB2 = (size_t)N_NODES * 128 * 2;   // 25.6 MB bf16 plane
    unsigned short* featb = (unsigned short*)p;  p += NB2;
    unsigned short* qb    = (unsigned short*)p;  p += NB2;
    unsigned short* kb    = (unsigned short*)p;  p += NB2;
    unsigned short* vb    = (unsigned short*)p;  p += NB2;
    float*          sk    = (float*)p;           p += (size_t)N_NODES * 128 * 4;
    unsigned short* Wtb   = (unsigned short*)p;  p += (size_t)4 * 128 * 128 * 2;
    int* sorted_src = (int*)p;  p += (size_t)N_EDGES * 4;
    int* counts     = (int*)p;  p += (size_t)N_NODES * 4;
    int* offs       = (int*)p;  p += (size_t)N_NODES * 4;
    int* cursor     = (int*)p;  p += (size_t)N_NODES * 4;
    int* bsums      = (int*)p;  p += 4096;
    int* bscan      = (int*)p;  p += 4096;

    hipMemsetAsync(counts, 0, (size_t)N_NODES * 4, stream);

    prep<<<19006, 256, 0, stream>>>(feat, dst, Wq, Wk, Wv, Wsk, featb, Wtb, counts);
    gemm_mfma<<<dim3(782, 4), 256, 0, stream>>>(featb, Wtb, bq, bk, bv, bsk,
                                                qb, kb, vb, sk);
    scan_block<<<NBLK_SCAN, 256, 0, stream>>>(counts, offs, bsums);
    scan_sums<<<1, 512, 0, stream>>>(bsums, bscan);
    add_back<<<NBLK_SCAN, 256, 0, stream>>>(offs, bscan, cursor);
    scatter_kernel<<<(N_EDGES + 255) / 256, 256, 0, stream>>>(src, dst, offs, cursor, sorted_src);
    node_fused<<<(N_NODES + 3) / 4, 256, 0, stream>>>(qb, kb, vb, sk, offs, sorted_src,
                                                      Wg, bg, gamma, beta, pa, out);
}

// Round 6
// 375.915 us; speedup vs baseline: 8.5212x; 1.0922x over previous
//
#include <hip/hip_runtime.h>
#include <hip/hip_bf16.h>
#include <hip/hip_fp16.h>
#include <math.h>

#define N_NODES 100000
#define N_EDGES 1600000
#define NBLK_SCAN 391   // ceil(100000/256)
// IN=128, HD=128, H=4, D=32

typedef __attribute__((ext_vector_type(8))) short bf16x8;
typedef __attribute__((ext_vector_type(4))) float f32x4;

__device__ __forceinline__ short f2bf_s(float x) {
    __hip_bfloat16 b = __float2bfloat16(x);
    return *reinterpret_cast<short*>(&b);
}
__device__ __forceinline__ __half2 bc2(unsigned u) {
    return *reinterpret_cast<__half2*>(&u);
}
__device__ __forceinline__ unsigned bcu(__half2 h) {
    return *reinterpret_cast<unsigned*>(&h);
}

// ============================================================
// prep: [dst histogram] + [W transpose -> bf16]
//   blocks 0..6249: histogram over 1.6M edges
//   blocks 6250..6505: Wtb[m][c][k] = W[m][k][c]  (65536 elems)
// ============================================================
__global__ __launch_bounds__(256) void prep(
    const int* __restrict__ dst,
    const float* __restrict__ Wq, const float* __restrict__ Wk,
    const float* __restrict__ Wv, const float* __restrict__ Ws,
    unsigned short* __restrict__ Wtb, int* __restrict__ counts)
{
    int bid = blockIdx.x;
    if (bid < 6250) {
        int e = bid * 256 + threadIdx.x;
        atomicAdd(&counts[dst[e]], 1);
    } else {
        int j = (bid - 6250) * 256 + threadIdx.x;   // [0, 65536)
        int m = j >> 14;
        int rem = j & 16383;
        int c = rem >> 7;
        int kk = rem & 127;
        const float* W = (m == 0) ? Wq : (m == 1) ? Wk : (m == 2) ? Wv : Ws;
        Wtb[j] = (unsigned short)f2bf_s(W[(size_t)kk * 128 + c]);
    }
}

// ============================================================
// MFMA GEMM: block = 32 rows, wave w computes mat w (all 128 cols)
//   A read from fp32 feat directly (converted in-register to bf16)
//   outputs fp16 (q/k/v/skip)
// ============================================================
__global__ __launch_bounds__(256) void gemm_mfma(
    const float* __restrict__ feat, const unsigned short* __restrict__ Wtb,
    const float* __restrict__ bq, const float* __restrict__ bk,
    const float* __restrict__ bv, const float* __restrict__ bs,
    __half* __restrict__ qh, __half* __restrict__ kh,
    __half* __restrict__ vh, __half* __restrict__ skh)
{
    const int mat = threadIdx.x >> 6;    // wave = matrix
    const int l   = threadIdx.x & 63;
    const int lr  = l & 15;
    const int lg  = l >> 4;
    const int r0  = blockIdx.x * 32;     // 3125 * 32 = 100000 exact
    const float* bias = (mat == 0) ? bq : (mat == 1) ? bk : (mat == 2) ? bv : bs;
    __half* outp      = (mat == 0) ? qh : (mat == 1) ? kh : (mat == 2) ? vh : skh;

    f32x4 acc[2][8];
    #pragma unroll
    for (int i = 0; i < 2; i++)
        #pragma unroll
        for (int j = 0; j < 8; j++) acc[i][j] = (f32x4){0.f, 0.f, 0.f, 0.f};

    #pragma unroll
    for (int ks = 0; ks < 4; ks++) {
        const int k0 = ks * 32 + lg * 8;
        bf16x8 a[2], b[8];
        #pragma unroll
        for (int rf = 0; rf < 2; rf++) {
            const float* fp = feat + (size_t)(r0 + rf * 16 + lr) * 128 + k0;
            float4 f0 = ((const float4*)fp)[0];
            float4 f1 = ((const float4*)fp)[1];
            a[rf] = (bf16x8){f2bf_s(f0.x), f2bf_s(f0.y), f2bf_s(f0.z), f2bf_s(f0.w),
                             f2bf_s(f1.x), f2bf_s(f1.y), f2bf_s(f1.z), f2bf_s(f1.w)};
        }
        #pragma unroll
        for (int cf = 0; cf < 8; cf++) {
            int col = cf * 16 + lr;
            b[cf] = *(const bf16x8*)(Wtb + ((size_t)mat * 128 + col) * 128 + k0);
        }
        #pragma unroll
        for (int rf = 0; rf < 2; rf++)
            #pragma unroll
            for (int cf = 0; cf < 8; cf++)
                acc[rf][cf] = __builtin_amdgcn_mfma_f32_16x16x32_bf16(
                    a[rf], b[cf], acc[rf][cf], 0, 0, 0);
    }

    // C/D layout: col = lane&15, row = (lane>>4)*4 + reg
    #pragma unroll
    for (int rf = 0; rf < 2; rf++) {
        #pragma unroll
        for (int cf = 0; cf < 8; cf++) {
            int col = cf * 16 + lr;
            float bv_ = bias[col];
            #pragma unroll
            for (int reg = 0; reg < 4; reg++) {
                int row = r0 + rf * 16 + lg * 4 + reg;
                outp[(size_t)row * 128 + col] = __float2half(acc[rf][cf][reg] + bv_);
            }
        }
    }
}

// ============================================================
// CSR: scan + scatter
// ============================================================
__global__ __launch_bounds__(256) void scan_block(
    const int* __restrict__ counts, int* __restrict__ offs, int* __restrict__ bsums)
{
    __shared__ int s[256];
    int i = blockIdx.x * 256 + threadIdx.x;
    int x = (i < N_NODES) ? counts[i] : 0;
    s[threadIdx.x] = x;
    __syncthreads();
    #pragma unroll
    for (int o = 1; o < 256; o <<= 1) {
        int t = (threadIdx.x >= o) ? s[threadIdx.x - o] : 0;
        __syncthreads();
        s[threadIdx.x] += t;
        __syncthreads();
    }
    if (i < N_NODES) offs[i] = s[threadIdx.x] - x;
    if (threadIdx.x == 255) bsums[blockIdx.x] = s[255];
}

__global__ __launch_bounds__(512) void scan_sums(
    int* __restrict__ bsums, int* __restrict__ bscan)
{
    __shared__ int s[512];
    int i = threadIdx.x;
    int x = (i < NBLK_SCAN) ? bsums[i] : 0;
    s[i] = x;
    __syncthreads();
    #pragma unroll
    for (int o = 1; o < 512; o <<= 1) {
        int t = (i >= o) ? s[i - o] : 0;
        __syncthreads();
        s[i] += t;
        __syncthreads();
    }
    if (i < NBLK_SCAN) bscan[i] = s[i] - x;
}

__global__ __launch_bounds__(256) void add_back(
    int* __restrict__ offs, const int* __restrict__ bscan, int* __restrict__ cursor)
{
    int i = blockIdx.x * 256 + threadIdx.x;
    if (i < N_NODES) {
        offs[i] += bscan[blockIdx.x];
        cursor[i] = 0;
    }
}

__global__ __launch_bounds__(256) void scatter_kernel(
    const int* __restrict__ src, const int* __restrict__ dst,
    const int* __restrict__ offs, int* __restrict__ cursor,
    int* __restrict__ sorted_src)
{
    int e = blockIdx.x * 256 + threadIdx.x;
    if (e >= N_EDGES) return;
    int dN = dst[e];
    int pos = offs[dN] + atomicAdd(&cursor[dN], 1);
    sorted_src[pos] = src[e];
}

// ============================================================
// fused dst-centric aggregation + gate + LN + PReLU
//   one wave per node; lane = (quarter, c): quarter-wave per edge
//   (4 edges/iter), lane owns elems 8c..8c+7 (head = c>>2)
//   packed fp16 math, 2-stage software-pipelined gathers,
//   softmax without max subtraction (scores bounded)
// ============================================================
__global__ __launch_bounds__(256) void node_fused(
    const __half* __restrict__ qh, const __half* __restrict__ kh,
    const __half* __restrict__ vh, const __half* __restrict__ skh,
    const int* __restrict__ offs, const int* __restrict__ sorted_src,
    const float* __restrict__ wg, const float* __restrict__ bg,
    const float* __restrict__ gamma, const float* __restrict__ beta,
    const float* __restrict__ pa, float* __restrict__ out)
{
    int wid = threadIdx.x >> 6;
    int l   = threadIdx.x & 63;
    int qtr = l >> 4;
    int c   = l & 15;
    int n = blockIdx.x * 4 + wid;
    if (n >= N_NODES) return;

    int start = offs[n];
    int end   = (n + 1 < N_NODES) ? offs[n + 1] : N_EDGES;

    const uint4* qrow = (const uint4*)qh;   // row = 16 uint4 chunks
    const uint4* vrow = (const uint4*)vh;

    uint4 kp = ((const uint4*)kh)[(size_t)n * 16 + c];
    __half2 kk0 = bc2(kp.x), kk1 = bc2(kp.y), kk2 = bc2(kp.z), kk3 = bc2(kp.w);

    float den = 0.f;
    __half2 ag0 = bc2(0u), ag1 = bc2(0u), ag2 = bc2(0u), ag3 = bc2(0u);
    const float C = 0.25503483f;   // (1/sqrt(32)) * log2(e)

    // software-pipelined loop: load group B while computing group A
    int baseA = start;
    uint4 qA, vA;
    {
        int cl = min(baseA + qtr, end - 1);
        int s = sorted_src[cl];
        qA = qrow[(size_t)s * 16 + c];
        vA = vrow[(size_t)s * 16 + c];
    }
    for (;;) {
        int baseB = baseA + 4;
        bool hasB = baseB < end;
        uint4 qB, vB;
        if (hasB) {
            int cl = min(baseB + qtr, end - 1);
            int s = sorted_src[cl];
            qB = qrow[(size_t)s * 16 + c];
            vB = vrow[(size_t)s * 16 + c];
        }
        // compute group A
        __half2 d2 = __hmul2(bc2(qA.x), kk0);
        d2 = __hfma2(bc2(qA.y), kk1, d2);
        d2 = __hfma2(bc2(qA.z), kk2, d2);
        d2 = __hfma2(bc2(qA.w), kk3, d2);
        d2 = __hadd2(d2, bc2(__shfl_xor(bcu(d2), 1)));
        d2 = __hadd2(d2, bc2(__shfl_xor(bcu(d2), 2)));
        float d = __low2float(d2) + __high2float(d2);
        float e = (baseA + qtr < end) ? __builtin_amdgcn_exp2f(d * C) : 0.f;
        den += e;
        __half2 e2 = __float2half2_rn(e);
        ag0 = __hfma2(e2, bc2(vA.x), ag0);
        ag1 = __hfma2(e2, bc2(vA.y), ag1);
        ag2 = __hfma2(e2, bc2(vA.z), ag2);
        ag3 = __hfma2(e2, bc2(vA.w), ag3);
        if (!hasB) break;
        baseA = baseB; qA = qB; vA = vB;
    }

    // merge the four quarters
    den += __shfl_xor(den, 16);
    den += __shfl_xor(den, 32);
    ag0 = __hadd2(ag0, bc2(__shfl_xor(bcu(ag0), 16)));
    ag1 = __hadd2(ag1, bc2(__shfl_xor(bcu(ag1), 16)));
    ag2 = __hadd2(ag2, bc2(__shfl_xor(bcu(ag2), 16)));
    ag3 = __hadd2(ag3, bc2(__shfl_xor(bcu(ag3), 16)));
    ag0 = __hadd2(ag0, bc2(__shfl_xor(bcu(ag0), 32)));
    ag1 = __hadd2(ag1, bc2(__shfl_xor(bcu(ag1), 32)));
    ag2 = __hadd2(ag2, bc2(__shfl_xor(bcu(ag2), 32)));
    ag3 = __hadd2(ag3, bc2(__shfl_xor(bcu(ag3), 32)));

    float rd = 1.f / den;
    float r[8];
    r[0] = __low2float(ag0) * rd; r[1] = __high2float(ag0) * rd;
    r[2] = __low2float(ag1) * rd; r[3] = __high2float(ag1) * rd;
    r[4] = __low2float(ag2) * rd; r[5] = __high2float(ag2) * rd;
    r[6] = __low2float(ag3) * rd; r[7] = __high2float(ag3) * rd;

    uint4 sp4 = ((const uint4*)skh)[(size_t)n * 16 + c];
    float s[8];
    s[0] = __low2float(bc2(sp4.x)); s[1] = __high2float(bc2(sp4.x));
    s[2] = __low2float(bc2(sp4.y)); s[3] = __high2float(bc2(sp4.y));
    s[4] = __low2float(bc2(sp4.z)); s[5] = __high2float(bc2(sp4.z));
    s[6] = __low2float(bc2(sp4.w)); s[7] = __high2float(bc2(sp4.w));

    const float4* wgf = (const float4*)wg;
    float4 w0a = wgf[2 * c],      w0b = wgf[2 * c + 1];
    float4 w1a = wgf[32 + 2 * c], w1b = wgf[32 + 2 * c + 1];
    float4 w2a = wgf[64 + 2 * c], w2b = wgf[64 + 2 * c + 1];
    float w0[8] = {w0a.x, w0a.y, w0a.z, w0a.w, w0b.x, w0b.y, w0b.z, w0b.w};
    float w1[8] = {w1a.x, w1a.y, w1a.z, w1a.w, w1b.x, w1b.y, w1b.z, w1b.w};
    float w2[8] = {w2a.x, w2a.y, w2a.z, w2a.w, w2b.x, w2b.y, w2b.z, w2b.w};

    float gs = 0.f;
    #pragma unroll
    for (int j = 0; j < 8; j++)
        gs += s[j] * w0[j] + r[j] * w1[j] + (s[j] - r[j]) * w2[j];
    gs += __shfl_xor(gs, 1);
    gs += __shfl_xor(gs, 2);
    gs += __shfl_xor(gs, 4);
    gs += __shfl_xor(gs, 8);
    float g = 1.f / (1.f + __builtin_amdgcn_exp2f(-(gs + bg[0]) * 1.4426950408889634f));

    #pragma unroll
    for (int j = 0; j < 8; j++) r[j] = g * s[j] + (1.f - g) * r[j];

    float mu = 0.f;
    #pragma unroll
    for (int j = 0; j < 8; j++) mu += r[j];
    mu += __shfl_xor(mu, 1);
    mu += __shfl_xor(mu, 2);
    mu += __shfl_xor(mu, 4);
    mu += __shfl_xor(mu, 8);
    mu *= (1.f / 128.f);

    float var = 0.f;
    #pragma unroll
    for (int j = 0; j < 8; j++) { float e0 = r[j] - mu; var += e0 * e0; }
    var += __shfl_xor(var, 1);
    var += __shfl_xor(var, 2);
    var += __shfl_xor(var, 4);
    var += __shfl_xor(var, 8);
    var *= (1.f / 128.f);
    float inv = rsqrtf(var + 1e-5f);

    if (qtr == 0) {
        float4 ga = ((const float4*)gamma)[2 * c], gb = ((const float4*)gamma)[2 * c + 1];
        float4 ba = ((const float4*)beta)[2 * c],  bb = ((const float4*)beta)[2 * c + 1];
        float gm[8] = {ga.x, ga.y, ga.z, ga.w, gb.x, gb.y, gb.z, gb.w};
        float bt[8] = {ba.x, ba.y, ba.z, ba.w, bb.x, bb.y, bb.z, bb.w};
        float al = pa[0];
        float y[8];
        #pragma unroll
        for (int j = 0; j < 8; j++) {
            float t = (r[j] - mu) * inv * gm[j] + bt[j];
            y[j] = (t > 0.f) ? t : al * t;
        }
        float4* op = (float4*)(out + (size_t)n * 128 + c * 8);
        op[0] = (float4){y[0], y[1], y[2], y[3]};
        op[1] = (float4){y[4], y[5], y[6], y[7]};
    }
}

// ============================================================
extern "C" void kernel_launch(void* const* d_in, const int* in_sizes, int n_in,
                              void* d_out, int out_size, void* d_ws, size_t ws_size,
                              hipStream_t stream) {
    const float* feat  = (const float*)d_in[0];
    const int*   src   = (const int*)d_in[1];
    const int*   dst   = (const int*)d_in[2];
    const float* Wq    = (const float*)d_in[3];
    const float* bq    = (const float*)d_in[4];
    const float* Wk    = (const float*)d_in[5];
    const float* bk    = (const float*)d_in[6];
    const float* Wv    = (const float*)d_in[7];
    const float* bv    = (const float*)d_in[8];
    const float* Wsk   = (const float*)d_in[9];
    const float* bsk   = (const float*)d_in[10];
    const float* Wg    = (const float*)d_in[11];
    const float* bg    = (const float*)d_in[12];
    const float* gamma = (const float*)d_in[13];
    const float* beta  = (const float*)d_in[14];
    const float* pa    = (const float*)d_in[15];
    float* out = (float*)d_out;

    char* p = (char*)d_ws;
    const size_t NH = (size_t)N_NODES * 128 * 2;   // 25.6 MB fp16 plane
    __half* qh  = (__half*)p;  p += NH;
    __half* kh  = (__half*)p;  p += NH;
    __half* vh  = (__half*)p;  p += NH;
    __half* skh = (__half*)p;  p += NH;
    unsigned short* Wtb = (unsigned short*)p;  p += (size_t)4 * 128 * 128 * 2;
    int* sorted_src = (int*)p;  p += (size_t)N_EDGES * 4;
    int* counts     = (int*)p;  p += (size_t)N_NODES * 4;
    int* offs       = (int*)p;  p += (size_t)N_NODES * 4;
    int* cursor     = (int*)p;  p += (size_t)N_NODES * 4;
    int* bsums      = (int*)p;  p += 4096;
    int* bscan      = (int*)p;  p += 4096;

    hipMemsetAsync(counts, 0, (size_t)N_NODES * 4, stream);

    prep<<<6506, 256, 0, stream>>>(dst, Wq, Wk, Wv, Wsk, Wtb, counts);
    gemm_mfma<<<3125, 256, 0, stream>>>(feat, Wtb, bq, bk, bv, bsk, qh, kh, vh, skh);
    scan_block<<<NBLK_SCAN, 256, 0, stream>>>(counts, offs, bsums);
    scan_sums<<<1, 512, 0, stream>>>(bsums, bscan);
    add_back<<<NBLK_SCAN, 256, 0, stream>>>(offs, bscan, cursor);
    scatter_kernel<<<(N_EDGES + 255) / 256, 256, 0, stream>>>(src, dst, offs, cursor, sorted_src);
    node_fused<<<(N_NODES + 3) / 4, 256, 0, stream>>>(qh, kh, vh, skh, offs, sorted_src,
                                                      Wg, bg, gamma, beta, pa, out);
}